// Round 1
// baseline (105.553 us; speedup 1.0000x reference)
//
#include <hip/hip_runtime.h>
#include <hip/hip_bf16.h>

// QConv1d: x (8,64,16384) f32, w (64,64,9) f32, bias (64) f32
// out (8,64,16384) f32 = conv1d(x, w, pad=4) * 0.125 + bias
// Strategy: cast to bf16 (weights pre-scaled by 0.125 — exact, power of two),
// MFMA f32_16x16x32_bf16, fp32 accumulate, fp32 out.
// Round-6: occupancy push. LTILE 256->128 (LDS 39->20.7 KB/block), grid
// 512->1024 blocks => 4 blocks/CU (16 waves) instead of 2 (8 waves), so the
// stage->sync->MFMA->store phases of neighboring blocks overlap on each CU.
// Wave layout kept (2 O-halves x 2 L-halves); staging unit shrunk to 8c x 4l
// so all 256 threads participate (288 units).
#define C_IN    64
#define L_IN    16384
#define O_OUT   64
#define KTAP    9
#define LTILE   128
#define ROWS    144      // LTILE + 16 halo rows (global l in [l0-8, l0+136))
#define RSTRIDE 72       // 64 + 8 pad (multiple of 8 -> 16B-aligned b128 rows)

typedef short          bf16x8 __attribute__((ext_vector_type(8)));   // MFMA A/B frag
typedef unsigned short u16x8  __attribute__((ext_vector_type(8)));
typedef unsigned int   u32x4  __attribute__((ext_vector_type(4)));
typedef float          f32x4  __attribute__((ext_vector_type(4)));   // MFMA C/D frag

static __device__ __forceinline__ unsigned short f2bf(float f) {
  __hip_bfloat16 h = __float2bfloat16(f);   // round-to-nearest
  return __builtin_bit_cast(unsigned short, h);
}

// pack two floats -> one u32 of two bf16 (lo in low 16 bits)
static __device__ __forceinline__ unsigned int pk2(float lo, float hi) {
  return (unsigned int)f2bf(lo) | ((unsigned int)f2bf(hi) << 16);
}

// ---------------------------------------------------------------------------
// Pre-kernel: w[o][c][t] fp32 (stride-9 taps) -> W2[t][o][c] bf16 (c contig),
// pre-scaled by 0.125 (exact: power-of-two only touches the exponent).
// ---------------------------------------------------------------------------
__global__ void w_rearrange(const float* __restrict__ w,
                            unsigned short* __restrict__ w2) {
    int i = blockIdx.x * 256 + threadIdx.x;       // i = t*4096 + o*64 + c
    if (i >= KTAP * O_OUT * C_IN) return;
    int t  = i >> 12;
    int oc = i & 4095;                            // o*64 + c
    w2[i] = f2bf(w[oc * KTAP + t] * 0.125f);
}

// ---------------------------------------------------------------------------
// Main kernel: one block = one n, one 128-wide L tile, all 64 outputs.
// 4 waves in a 2(O) x 2(L) grid; each wave owns 32 O x 64 L.
// ---------------------------------------------------------------------------
__global__ __launch_bounds__(256, 4) void qconv_kernel(
    const float* __restrict__ x,
    const unsigned short* __restrict__ w2,    // bf16 bits, pre-scaled
    const float* __restrict__ bias,
    float* __restrict__ out) {

  __shared__ __align__(16) unsigned short xs[ROWS][RSTRIDE];  // bf16 x tile, [l][c]

  const int tid = threadIdx.x;
  const int n   = blockIdx.x >> 7;             // 128 tiles per n
  const int l0  = (blockIdx.x & 127) << 7;     // tile base along L
  const float* xn = x + (size_t)n * C_IN * L_IN;

  // ---- Phase 1: stage x tile into LDS, fp32->bf16, transposed to [l][c] --
  // 288 8x4 transpose units (8 channels x 4 l); pair-packed bf16 conversion
  // along c so each LDS row word is one pack op.
  for (int idx = tid; idx < 8 * (ROWS / 4); idx += 256) {
    const int cb = idx & 7;
    const int lb = idx >> 3;                   // 0..35
    const int c0 = cb << 3;
    const int gl0 = l0 - 8 + (lb << 2);        // global l of first row (16B-aligned)
    if (gl0 >= 0 && gl0 + 4 <= L_IN) {
      f32x4 v[8];
#pragma unroll
      for (int i = 0; i < 8; ++i)
        v[i] = *reinterpret_cast<const f32x4*>(xn + (size_t)(c0 + i) * L_IN + gl0);
#pragma unroll
      for (int j = 0; j < 4; ++j) {
        u32x4 wv;
#pragma unroll
        for (int p = 0; p < 4; ++p)
          wv[p] = pk2(v[2 * p][j], v[2 * p + 1][j]);
        *reinterpret_cast<u32x4*>(&xs[(lb << 2) + j][c0]) = wv;
      }
    } else {
      // edge tiles only: element-wise zero-fill outside [0, L)
      unsigned short vb[8][4];                  // [i=c][j=l]
      for (int i = 0; i < 8; ++i)
        for (int j = 0; j < 4; ++j) {
          int gl = gl0 + j;
          vb[i][j] = (gl >= 0 && gl < L_IN)
                         ? f2bf(xn[(size_t)(c0 + i) * L_IN + gl])
                         : (unsigned short)0;
        }
      for (int j = 0; j < 4; ++j) {
        u16x8 wv;
        for (int i = 0; i < 8; ++i) wv[i] = vb[i][j];
        *reinterpret_cast<u16x8*>(&xs[(lb << 2) + j][c0]) = wv;
      }
    }
  }
  __syncthreads();

  // ---- Phase 2: MFMA main loop ------------------------------------------
  const int wave = tid >> 6;
  const int lane = tid & 63;
  const int wr   = wave >> 1;       // O half: o in [32*wr, 32*wr+32)
  const int wc   = wave & 1;        // L half: l-offset wc*64
  const int col  = lane & 15;
  const int quad = lane >> 4;

  f32x4 acc[2][4];
#pragma unroll
  for (int m = 0; m < 2; ++m)
#pragma unroll
    for (int lt = 0; lt < 4; ++lt) acc[m][lt] = (f32x4){0.f, 0.f, 0.f, 0.f};

  // LDS row for out-col l = l0 + wc*64 + lt*16 + col at tap t:
  //   r = (l + t - 4) - (l0 - 8) = wc*64 + lt*16 + col + t + 4
  const int rbase = (wc << 6) + col + 4;

  for (int t = 0; t < KTAP; ++t) {
    // A-frags: W2[t][o][c]; lane holds o = o0+col, c = k*32 + quad*8 .. +7
    bf16x8 a[2][2];
#pragma unroll
    for (int m = 0; m < 2; ++m)
#pragma unroll
      for (int k = 0; k < 2; ++k)
        a[m][k] = *reinterpret_cast<const bf16x8*>(
            w2 + (t << 12) + (((wr << 5) + (m << 4) + col) << 6) + (k << 5) + (quad << 3));

#pragma unroll
    for (int k = 0; k < 2; ++k) {
#pragma unroll
      for (int lt = 0; lt < 4; ++lt) {
        const int r = rbase + t + (lt << 4);
        const bf16x8 b = *reinterpret_cast<const bf16x8*>(&xs[r][(k << 5) + (quad << 3)]);
        acc[0][lt] = __builtin_amdgcn_mfma_f32_16x16x32_bf16(a[0][k], b, acc[0][lt], 0, 0, 0);
        acc[1][lt] = __builtin_amdgcn_mfma_f32_16x16x32_bf16(a[1][k], b, acc[1][lt], 0, 0, 0);
      }
    }
  }

  // ---- Phase 3: epilogue: + bias (0.125 folded into w), fp32 store ------
  // D layout: col = lane&15 -> l, row = quad*4 + reg -> o
#pragma unroll
  for (int m = 0; m < 2; ++m) {
    const int obase = (wr << 5) + (m << 4) + (quad << 2);
    float bv[4];
#pragma unroll
    for (int reg = 0; reg < 4; ++reg) bv[reg] = bias[obase + reg];
#pragma unroll
    for (int lt = 0; lt < 4; ++lt) {
      const int l = l0 + (wc << 6) + (lt << 4) + col;
#pragma unroll
      for (int reg = 0; reg < 4; ++reg) {
        const int o = obase + reg;
        out[((size_t)(n * O_OUT + o) << 14) + l] = acc[m][lt][reg] + bv[reg];
      }
    }
  }
}

extern "C" void kernel_launch(void* const* d_in, const int* in_sizes, int n_in,
                              void* d_out, int out_size, void* d_ws, size_t ws_size,
                              hipStream_t stream) {
  const float*    x    = (const float*)d_in[0];
  const float*    w    = (const float*)d_in[1];
  const float*    bias = (const float*)d_in[2];
  float*          out  = (float*)d_out;
  unsigned short* w2   = (unsigned short*)d_ws;   // 73728 B scratch (bf16 weights)

  // 1) rearrange + downcast + pre-scale weights into d_ws (runs every call)
  w_rearrange<<<(KTAP * O_OUT * C_IN + 255) / 256, 256, 0, stream>>>(w, w2);

  // 2) fused conv-as-GEMM: 8 n * 128 L-tiles = 1024 blocks
  qconv_kernel<<<8 * (L_IN / LTILE), 256, 0, stream>>>(x, w2, bias, out);
}

// Round 2
// 98.001 us; speedup vs baseline: 1.0771x; 1.0771x over previous
//
#include <hip/hip_runtime.h>
#include <hip/hip_bf16.h>

// QConv1d: x (8,64,16384) f32, w (64,64,9) f32, bias (64) f32
// out (8,64,16384) f32 = conv1d(x, w, pad=4) * 0.125 + bias
// Strategy: cast to bf16 (weights pre-scaled by 0.125 — exact, power of two),
// MFMA f32_16x16x32_bf16, fp32 accumulate, fp32 out.
// Round-7: revert to LTILE=256 (round-0 best; round-6's occupancy push
// regressed) and attack INTRA-block phase serialization instead (T14
// async-stage split):
//   - tile split into half A (rows 0..143 -> LDS directly) and half B
//     (rows 144..271): B's global loads are issued BEFORE compute-A and
//     held in registers; converted+written to LDS after compute-A.
//     compute-A reads rows 4..139 only => disjoint from B writes, no extra
//     barrier needed between them.
//   - store-A moved after the second barrier so its global writes overlap
//     compute-B.
//   - wave layout 4 waves x (16 O x 128 L); both L-halves computed
//     sequentially per wave => acc is 32 VGPRs (was 64), freeing room for
//     the 32 in-flight B-stage registers.
#define C_IN    64
#define L_IN    16384
#define O_OUT   64
#define KTAP    9
#define LTILE   256
#define ROWS    272      // LTILE + 16 halo rows (global l in [l0-8, l0+264))
#define AROWS   144      // rows [0,144) staged directly; [144,272) reg-staged
#define RSTRIDE 72       // 64 + 8 pad (multiple of 8 -> 16B-aligned b128 rows)

typedef short          bf16x8 __attribute__((ext_vector_type(8)));   // MFMA A/B frag
typedef unsigned int   u32x4  __attribute__((ext_vector_type(4)));
typedef float          f32x4  __attribute__((ext_vector_type(4)));   // MFMA C/D frag

static __device__ __forceinline__ unsigned short f2bf(float f) {
  __hip_bfloat16 h = __float2bfloat16(f);   // round-to-nearest
  return __builtin_bit_cast(unsigned short, h);
}

// pack two floats -> one u32 of two bf16 (lo in low 16 bits)
static __device__ __forceinline__ unsigned int pk2(float lo, float hi) {
  return (unsigned int)f2bf(lo) | ((unsigned int)f2bf(hi) << 16);
}

// ---------------------------------------------------------------------------
// Pre-kernel: w[o][c][t] fp32 (stride-9 taps) -> W2[t][o][c] bf16 (c contig),
// pre-scaled by 0.125 (exact: power-of-two only touches the exponent).
// ---------------------------------------------------------------------------
__global__ void w_rearrange(const float* __restrict__ w,
                            unsigned short* __restrict__ w2) {
    int i = blockIdx.x * 256 + threadIdx.x;       // i = t*4096 + o*64 + c
    if (i >= KTAP * O_OUT * C_IN) return;
    int t  = i >> 12;
    int oc = i & 4095;                            // o*64 + c
    w2[i] = f2bf(w[oc * KTAP + t] * 0.125f);
}

// ---------------------------------------------------------------------------
// Main kernel: one block = one n, one 256-wide L tile, all 64 outputs.
// 4 waves, each owning 16 O rows; the two 128-wide L halves are computed
// sequentially with memory traffic overlapped against MFMA.
// ---------------------------------------------------------------------------
__global__ __launch_bounds__(256) void qconv_kernel(
    const float* __restrict__ x,
    const unsigned short* __restrict__ w2,    // bf16 bits, pre-scaled
    const float* __restrict__ bias,
    float* __restrict__ out) {

  __shared__ __align__(16) unsigned short xs[ROWS][RSTRIDE];  // bf16 x tile, [l][c]

  const int tid = threadIdx.x;
  const int n   = blockIdx.x >> 6;
  const int l0  = (blockIdx.x & 63) << 8;      // tile base along L
  const float* xn = x + (size_t)n * C_IN * L_IN;

  // ---- Issue phase: all global loads for this tile ----------------------
  // Staging unit = 8 channels x 4 l (8x f32x4 loads). A region rows [0,144)
  // = 288 units (tid<32 take a second unit); B region rows [144,272) = 256
  // units, one per thread, held in registers through compute-A.
  const int ucb = tid & 7;            // channel block (c0 = ucb*8)
  const int ulb = tid >> 3;           // l block within region (0..31)
  const int uc0 = ucb << 3;

  // A unit 0 (rows ulb*4 .. +3)
  const int a0_gl0 = l0 - 8 + (ulb << 2);
  const bool a0_ok = (a0_gl0 >= 0) && (a0_gl0 + 4 <= L_IN);
  f32x4 va0[8];
  if (a0_ok) {
#pragma unroll
    for (int i = 0; i < 8; ++i)
      va0[i] = *reinterpret_cast<const f32x4*>(xn + (size_t)(uc0 + i) * L_IN + a0_gl0);
  }
  // A unit 1 (tid < 32): rows 128 + (tid>>3)*4 .. +3  — always in-bounds
  const bool have1 = (tid < 32);
  const int a1_gl0 = l0 - 8 + ((32 + ulb) << 2);   // only meaningful for tid<32
  f32x4 va1[8];
  if (have1) {
#pragma unroll
    for (int i = 0; i < 8; ++i)
      va1[i] = *reinterpret_cast<const f32x4*>(xn + (size_t)(uc0 + i) * L_IN + a1_gl0);
  }
  // B unit: rows 144 + ulb*4 .. +3 (gl0 >= 136 >= 0 always)
  const int b_gl0 = l0 + 136 + (ulb << 2);
  const bool b_ok = (b_gl0 + 4 <= L_IN);
  f32x4 vb[8];
  if (b_ok) {
#pragma unroll
    for (int i = 0; i < 8; ++i)
      vb[i] = *reinterpret_cast<const f32x4*>(xn + (size_t)(uc0 + i) * L_IN + b_gl0);
  }

  // ---- Convert + write half A to LDS ------------------------------------
  if (a0_ok) {
#pragma unroll
    for (int j = 0; j < 4; ++j) {
      u32x4 wv;
#pragma unroll
      for (int p = 0; p < 4; ++p)
        wv[p] = pk2(va0[2 * p][j], va0[2 * p + 1][j]);
      *reinterpret_cast<u32x4*>(&xs[(ulb << 2) + j][uc0]) = wv;
    }
  } else {
    // edge tiles only: element-wise zero-fill outside [0, L)
#pragma unroll
    for (int j = 0; j < 4; ++j) {
      const int gl = a0_gl0 + j;
      u32x4 wv;
#pragma unroll
      for (int p = 0; p < 4; ++p) {
        float lo = 0.f, hi = 0.f;
        if (gl >= 0 && gl < L_IN) {
          lo = xn[(size_t)(uc0 + 2 * p)     * L_IN + gl];
          hi = xn[(size_t)(uc0 + 2 * p + 1) * L_IN + gl];
        }
        wv[p] = pk2(lo, hi);
      }
      *reinterpret_cast<u32x4*>(&xs[(ulb << 2) + j][uc0]) = wv;
    }
  }
  if (have1) {
#pragma unroll
    for (int j = 0; j < 4; ++j) {
      u32x4 wv;
#pragma unroll
      for (int p = 0; p < 4; ++p)
        wv[p] = pk2(va1[2 * p][j], va1[2 * p + 1][j]);
      *reinterpret_cast<u32x4*>(&xs[128 + (ulb << 2) + j][uc0]) = wv;
    }
  }
  __syncthreads();

  // ---- Compute ----------------------------------------------------------
  const int wave = tid >> 6;
  const int lane = tid & 63;
  const int col  = lane & 15;
  const int quad = lane >> 4;

  // A-frags: W2[t][o][c]; lane holds o = wave*16 + col, c = k*32 + quad*8 ..+7
  const unsigned short* wbase = w2 + (((wave << 4) + col) << 6) + (quad << 3);
  const int obase = (wave << 4) + (quad << 2);
  float bv[4];
#pragma unroll
  for (int reg = 0; reg < 4; ++reg) bv[reg] = bias[obase + reg];

  f32x4 acc[8];
#pragma unroll
  for (int lt = 0; lt < 8; ++lt) acc[lt] = (f32x4){0.f, 0.f, 0.f, 0.f};

  // -- half A: out cols l0 .. l0+127; LDS rows r = col + t + 4 + lt*16 ----
  for (int t = 0; t < KTAP; ++t) {
    bf16x8 a[2];
#pragma unroll
    for (int k = 0; k < 2; ++k)
      a[k] = *reinterpret_cast<const bf16x8*>(wbase + (t << 12) + (k << 5));
#pragma unroll
    for (int k = 0; k < 2; ++k) {
#pragma unroll
      for (int lt = 0; lt < 8; ++lt) {
        const int r = col + t + 4 + (lt << 4);
        const bf16x8 b = *reinterpret_cast<const bf16x8*>(&xs[r][(k << 5) + (quad << 3)]);
        acc[lt] = __builtin_amdgcn_mfma_f32_16x16x32_bf16(a[k], b, acc[lt], 0, 0, 0);
      }
    }
  }

  // ---- Convert + write half B to LDS (rows 144..271 — disjoint from the
  //      rows 4..139 compute-A just read, so no barrier needed above) -----
  if (b_ok) {
#pragma unroll
    for (int j = 0; j < 4; ++j) {
      u32x4 wv;
#pragma unroll
      for (int p = 0; p < 4; ++p)
        wv[p] = pk2(vb[2 * p][j], vb[2 * p + 1][j]);
      *reinterpret_cast<u32x4*>(&xs[144 + (ulb << 2) + j][uc0]) = wv;
    }
  } else {
    // right-edge tiles only
#pragma unroll
    for (int j = 0; j < 4; ++j) {
      const int gl = b_gl0 + j;
      u32x4 wv;
#pragma unroll
      for (int p = 0; p < 4; ++p) {
        float lo = 0.f, hi = 0.f;
        if (gl < L_IN) {
          lo = xn[(size_t)(uc0 + 2 * p)     * L_IN + gl];
          hi = xn[(size_t)(uc0 + 2 * p + 1) * L_IN + gl];
        }
        wv[p] = pk2(lo, hi);
      }
      *reinterpret_cast<u32x4*>(&xs[144 + (ulb << 2) + j][uc0]) = wv;
    }
  }
  __syncthreads();

  // ---- store half A (global writes fly under compute-B) -----------------
#pragma unroll
  for (int lt = 0; lt < 8; ++lt) {
    const int l = l0 + (lt << 4) + col;
#pragma unroll
    for (int reg = 0; reg < 4; ++reg)
      out[((size_t)(n * O_OUT + obase + reg) << 14) + l] = acc[lt][reg] + bv[reg];
  }

  // -- half B: out cols l0+128 .. l0+255; rows r = 128 + col + t + 4 + lt*16
#pragma unroll
  for (int lt = 0; lt < 8; ++lt) acc[lt] = (f32x4){0.f, 0.f, 0.f, 0.f};

  for (int t = 0; t < KTAP; ++t) {
    bf16x8 a[2];
#pragma unroll
    for (int k = 0; k < 2; ++k)
      a[k] = *reinterpret_cast<const bf16x8*>(wbase + (t << 12) + (k << 5));
#pragma unroll
    for (int k = 0; k < 2; ++k) {
#pragma unroll
      for (int lt = 0; lt < 8; ++lt) {
        const int r = 128 + col + t + 4 + (lt << 4);
        const bf16x8 b = *reinterpret_cast<const bf16x8*>(&xs[r][(k << 5) + (quad << 3)]);
        acc[lt] = __builtin_amdgcn_mfma_f32_16x16x32_bf16(a[k], b, acc[lt], 0, 0, 0);
      }
    }
  }

  // ---- store half B -----------------------------------------------------
#pragma unroll
  for (int lt = 0; lt < 8; ++lt) {
    const int l = l0 + 128 + (lt << 4) + col;
#pragma unroll
    for (int reg = 0; reg < 4; ++reg)
      out[((size_t)(n * O_OUT + obase + reg) << 14) + l] = acc[lt][reg] + bv[reg];
  }
}

extern "C" void kernel_launch(void* const* d_in, const int* in_sizes, int n_in,
                              void* d_out, int out_size, void* d_ws, size_t ws_size,
                              hipStream_t stream) {
  const float*    x    = (const float*)d_in[0];
  const float*    w    = (const float*)d_in[1];
  const float*    bias = (const float*)d_in[2];
  float*          out  = (float*)d_out;
  unsigned short* w2   = (unsigned short*)d_ws;   // 73728 B scratch (bf16 weights)

  // 1) rearrange + downcast + pre-scale weights into d_ws (runs every call)
  w_rearrange<<<(KTAP * O_OUT * C_IN + 255) / 256, 256, 0, stream>>>(w, w2);

  // 2) fused conv-as-GEMM: 8 n * 64 L-tiles = 512 blocks
  qconv_kernel<<<8 * (L_IN / LTILE), 256, 0, stream>>>(x, w2, bias, out);
}